// Round 2
// baseline (553.809 us; speedup 1.0000x reference)
//
#include <hip/hip_runtime.h>
#include <math.h>

#define N_INST 2048
#define N_REL  1024
#define FEAT   50176   // 256*14*14
#define FEAT4  12544   // FEAT/4
#define IPB    2       // instances per block

// ---------------- kernel 1: zero the used-instance flags ----------------
__global__ void init_flags_kernel(int* __restrict__ flags) {
    int n = blockIdx.x * blockDim.x + threadIdx.x;
    if (n < N_INST) flags[n] = 0;
}

// ---------------- kernel 2: mark instances referenced by any pair -------
__global__ void mark_used_kernel(const int* __restrict__ pairs, int* __restrict__ flags) {
    int t = blockIdx.x * blockDim.x + threadIdx.x;
    if (t < 2 * N_REL) flags[pairs[t]] = 1;   // same-value stores, no atomic needed
}

// ---------------- kernel 3: per-instance dual dot products --------------
// dA[n] = mf[n] . w[0:FEAT],  dB[n] = mf[n] . w[FEAT:2*FEAT]
// One block handles IPB=2 consecutive instances so each w element fetched
// from L2 is reused for 2 mask rows. Unused instances are skipped entirely
// (wave-uniform branch; flags identical across the block).
__global__ __launch_bounds__(256) void dual_dot_kernel(
    const float* __restrict__ mf, const float* __restrict__ w,
    const int* __restrict__ flags, float* __restrict__ dA, float* __restrict__ dB)
{
    const int n0 = blockIdx.x * IPB;
    const int used0 = flags[n0];
    const int used1 = flags[n0 + 1];
    if (!(used0 | used1)) return;

    const float4* __restrict__ wA = (const float4*)w;
    const float4* __restrict__ wB = (const float4*)(w + FEAT);
    const float4* __restrict__ r0 = (const float4*)(mf + (size_t)n0 * FEAT);
    const float4* __restrict__ r1 = (const float4*)(mf + (size_t)(n0 + 1) * FEAT);

    float sA0 = 0.f, sB0 = 0.f, sA1 = 0.f, sB1 = 0.f;
    for (int k = threadIdx.x; k < FEAT4; k += 256) {
        float4 a = wA[k];
        float4 b = wB[k];
        if (used0) {
            float4 m = r0[k];
            sA0 += m.x*a.x + m.y*a.y + m.z*a.z + m.w*a.w;
            sB0 += m.x*b.x + m.y*b.y + m.z*b.z + m.w*b.w;
        }
        if (used1) {
            float4 m = r1[k];
            sA1 += m.x*a.x + m.y*a.y + m.z*a.z + m.w*a.w;
            sB1 += m.x*b.x + m.y*b.y + m.z*b.z + m.w*b.w;
        }
    }

    // wave-level reduction (64 lanes)
    for (int off = 32; off; off >>= 1) {
        sA0 += __shfl_down(sA0, off, 64);
        sB0 += __shfl_down(sB0, off, 64);
        sA1 += __shfl_down(sA1, off, 64);
        sB1 += __shfl_down(sB1, off, 64);
    }
    __shared__ float red[4][4];
    const int wid = threadIdx.x >> 6;
    if ((threadIdx.x & 63) == 0) {
        red[wid][0] = sA0; red[wid][1] = sB0;
        red[wid][2] = sA1; red[wid][3] = sB1;
    }
    __syncthreads();
    if (threadIdx.x == 0) {
        float a0 = 0.f, b0 = 0.f, a1 = 0.f, b1 = 0.f;
        for (int q = 0; q < 4; ++q) {
            a0 += red[q][0]; b0 += red[q][1];
            a1 += red[q][2]; b1 += red[q][3];
        }
        if (used0) { dA[n0]     = a0; dB[n0]     = b0; }
        if (used1) { dA[n0 + 1] = a1; dB[n0 + 1] = b1; }
    }
}

// ---------------- kernel 4: logits -> BCE -> mean -----------------------
__device__ __forceinline__ float softplus_f(float x) {
    // numerically stable softplus(x) = log(1 + e^x)
    return fmaxf(x, 0.f) + log1pf(expf(-fabsf(x)));
}

__global__ __launch_bounds__(1024) void bce_kernel(
    const int* __restrict__ pairs, const float* __restrict__ dA,
    const float* __restrict__ dB, const float* __restrict__ bptr,
    float* __restrict__ out)
{
    const int t = threadIdx.x;               // 0..1023, one pair per thread
    const float bb = bptr[0];
    const int i = pairs[2 * t];
    const int j = pairs[2 * t + 1];
    const float lf = dA[i] + dB[j] + bb;     // target = 1 -> bce = softplus(-x)
    const float lr = dA[j] + dB[i] + bb;     // target = 0 -> bce = softplus(+x)
    float v = softplus_f(-lf) + softplus_f(lr);

    for (int off = 32; off; off >>= 1) v += __shfl_down(v, off, 64);
    __shared__ float red[16];
    if ((t & 63) == 0) red[t >> 6] = v;
    __syncthreads();
    if (t < 16) {
        float x = red[t];
        for (int off = 8; off; off >>= 1) x += __shfl_down(x, off, 16);
        if (t == 0) out[0] = x * (1.0f / (2 * N_REL));
    }
}

extern "C" void kernel_launch(void* const* d_in, const int* in_sizes, int n_in,
                              void* d_out, int out_size, void* d_ws, size_t ws_size,
                              hipStream_t stream) {
    const float* mf    = (const float*)d_in[0];   // (2048, 256, 14, 14) f32
    const int*   pairs = (const int*)d_in[1];     // (1024, 2) int
    const float* w     = (const float*)d_in[2];   // (100352,) f32
    const float* b     = (const float*)d_in[3];   // (1,) f32
    float* out = (float*)d_out;                   // scalar loss

    float* dA    = (float*)d_ws;                  // 2048 f32
    float* dB    = dA + N_INST;                   // 2048 f32
    int*   flags = (int*)(dB + N_INST);           // 2048 int

    init_flags_kernel<<<(N_INST + 255) / 256, 256, 0, stream>>>(flags);
    mark_used_kernel<<<(2 * N_REL + 255) / 256, 256, 0, stream>>>(pairs, flags);
    dual_dot_kernel<<<N_INST / IPB, 256, 0, stream>>>(mf, w, flags, dA, dB);
    bce_kernel<<<1, 1024, 0, stream>>>(pairs, dA, dB, b, out);
}